// Round 7
// baseline (115.620 us; speedup 1.0000x reference)
//
#include <hip/hip_runtime.h>

// YOLOv3 decode, fused single kernel: 3 scales (g=13,26,52), B=64,
// 3 anchors x (80 classes + 5).
// Outputs (concatenated flat, f32):
//   box_pred [64][3549][3][4]
//   box_conf [64][3549][3][1]
//   box_prob [64][3549][3][80]  (softmax over classes, no-max variant)
//
// R6: request-rate attack. R5's stores were 8B at 40B stride (~640 write
// requests/wave ~= 58us of issue). Now:
//  - INTERLEAVED classes: lane h owns {h, h+16, ...}; a store instr has 16
//    lanes writing 4B contiguous (64B segments) -> ~80 requests/wave.
//  - float4 reads x 4 positions (g52/g26): 5 load instr/lane, 16B/lane,
//    still 20 live floats (VGPR budget), shfl_xor 1,2,4,8 butterfly.
//  - bijective XCD block swizzle (13816 blocks % 8 == 0): halves of shared
//    128B lines land on the same XCD L2 (no double fetch / write RMW).

namespace {

constexpr int BATCH   = 64;
constexpr int S_TOTAL = 3549;           // 169 + 676 + 2704
constexpr int NC      = 80;
constexpr long long PRED_TOTAL = (long long)BATCH * S_TOTAL * 3 * 4;  // 2,725,632
constexpr long long CONF_TOTAL = (long long)BATCH * S_TOTAL * 3;      //   681,408

constexpr int N52T = BATCH * 3 * (52 * 52 / 4) * 16;  // 2,076,672
constexpr int N26T = BATCH * 3 * (26 * 26 / 4) * 16;  //   519,168
constexpr int N13T = BATCH * 3 * (13 * 13) * 8;       //   259,584
constexpr int NPRD = BATCH * S_TOTAL * 3;             //   681,408
constexpr int NTOT = N52T + N26T + N13T + NPRD;       // 3,536,832
constexpr int NBLK = (NTOT + 255) / 256;              // 13,816 (== 0 mod 8)

__device__ __forceinline__ float sigmoidf_(float x) {
    return __builtin_amdgcn_rcpf(1.0f + __expf(-x));
}

// ---- classes: 16-lane group x 4 positions, float4 loads (G^2 % 4 == 0) ----
// lane h owns classes {h, h+16, h+32, h+48, h+64}
template <int G, int S_OFF>
__device__ __forceinline__ void cls16x4(int tid,
                                        const float* __restrict__ feat,
                                        float* __restrict__ out)
{
    constexpr int G2 = G * G;
    constexpr int NQ = G2 / 4;

    const int h   = tid & 15;
    const int grp = tid >> 4;
    const int q   = grp % NQ;
    const int ba  = grp / NQ;
    const int a   = ba % 3;
    const int b   = ba / 3;
    const int s0  = q * 4;

    const float* __restrict__ pc =
        feat + (size_t)(b * 255 + a * 85 + 5 + h) * G2 + s0;

    float4 cls[5];
#pragma unroll
    for (int k = 0; k < 5; ++k)
        cls[k] = *(const float4*)(pc + (size_t)(k * 16) * G2);

    // exp as loads land; pin results (20 live floats, no remat/spill)
    float smx = 0.f, smy = 0.f, smz = 0.f, smw = 0.f;
#pragma unroll
    for (int k = 0; k < 5; ++k) {
        cls[k].x = __expf(cls[k].x);
        cls[k].y = __expf(cls[k].y);
        cls[k].z = __expf(cls[k].z);
        cls[k].w = __expf(cls[k].w);
        asm volatile("" : "+v"(cls[k].x), "+v"(cls[k].y),
                          "+v"(cls[k].z), "+v"(cls[k].w));
        smx += cls[k].x; smy += cls[k].y; smz += cls[k].z; smw += cls[k].w;
    }

#pragma unroll
    for (int d = 1; d <= 8; d <<= 1) {
        smx += __shfl_xor(smx, d, 64);
        smy += __shfl_xor(smy, d, 64);
        smz += __shfl_xor(smz, d, 64);
        smw += __shfl_xor(smw, d, 64);
    }
    const float r0 = __builtin_amdgcn_rcpf(smx);
    const float r1 = __builtin_amdgcn_rcpf(smy);
    const float r2 = __builtin_amdgcn_rcpf(smz);
    const float r3 = __builtin_amdgcn_rcpf(smw);

    const long long bsa0 = ((long long)b * S_TOTAL + (S_OFF + s0)) * 3 + a;
    float* __restrict__ pr = out + PRED_TOTAL + CONF_TOTAL + bsa0 * NC + h;

    // class c = h + 16k at position s0+p: 16 lanes write 4B contiguous
#pragma unroll
    for (int p = 0; p < 4; ++p) {
        const float rr = (p == 0) ? r0 : (p == 1) ? r1 : (p == 2) ? r2 : r3;
        float* __restrict__ prp = pr + (size_t)p * (3 * NC);
#pragma unroll
        for (int k = 0; k < 5; ++k) {
            const float v = ((p == 0) ? cls[k].x : (p == 1) ? cls[k].y
                              : (p == 2) ? cls[k].z : cls[k].w) * rr;
            prp[k * 16] = v;
        }
    }
}

// ---- classes: 8-lane group x 1 position, scalar loads (g=13, odd G^2) ----
// lane h owns classes {h, h+8, ..., h+72}
template <int G, int S_OFF>
__device__ __forceinline__ void cls8x1(int tid,
                                       const float* __restrict__ feat,
                                       float* __restrict__ out)
{
    constexpr int G2 = G * G;

    const int h   = tid & 7;
    const int pos = tid >> 3;
    const int s   = pos % G2;
    const int ba  = pos / G2;
    const int a   = ba % 3;
    const int b   = ba / 3;

    const float* __restrict__ pc =
        feat + (size_t)(b * 255 + a * 85 + 5 + h) * G2 + s;

    float cls[10];
#pragma unroll
    for (int k = 0; k < 10; ++k)
        cls[k] = pc[(size_t)(k * 8) * G2];

    float sum = 0.0f;
#pragma unroll
    for (int k = 0; k < 10; ++k) {
        cls[k] = __expf(cls[k]);
        asm volatile("" : "+v"(cls[k]));
        sum += cls[k];
    }
    sum += __shfl_xor(sum, 1, 64);
    sum += __shfl_xor(sum, 2, 64);
    sum += __shfl_xor(sum, 4, 64);
    const float rs = __builtin_amdgcn_rcpf(sum);

    const long long bsa = ((long long)b * S_TOTAL + (S_OFF + s)) * 3 + a;
    float* __restrict__ pr = out + PRED_TOTAL + CONF_TOTAL + bsa * NC + h;
#pragma unroll
    for (int k = 0; k < 10; ++k)
        pr[k * 8] = cls[k] * rs;
}

// ---- pred + conf: thread == bsa, fully coalesced float4/scalar writes ----
__device__ __forceinline__ void pred_conf(int tid,
                                          const float* __restrict__ f13,
                                          const float* __restrict__ f26,
                                          const float* __restrict__ f52,
                                          float* __restrict__ out)
{
    const int a  = tid % 3;
    const int r  = tid / 3;
    const int sg = r % S_TOTAL;
    const int b  = r / S_TOTAL;

    float tx, ty, tw, th, tc, fx, fy, invG, aw, ah;
    if (sg < 169) {                     // g=13, anchors[6:9]/32
        constexpr int G2 = 169;
        const int s = sg;
        const float* __restrict__ p = f13 + (size_t)(b * 255 + a * 85) * G2 + s;
        tx = p[0]; ty = p[G2]; tw = p[2 * G2]; th = p[3 * G2]; tc = p[4 * G2];
        fx = (float)(s % 13); fy = (float)(s / 13); invG = 1.0f / 13.0f;
        aw = (a == 0) ? 3.625f  : ((a == 1) ? 4.875f  : 11.65625f);
        ah = (a == 0) ? 2.8125f : ((a == 1) ? 6.1875f : 10.1875f);
    } else if (sg < 845) {              // g=26, anchors[3:6]/16
        constexpr int G2 = 676;
        const int s = sg - 169;
        const float* __restrict__ p = f26 + (size_t)(b * 255 + a * 85) * G2 + s;
        tx = p[0]; ty = p[G2]; tw = p[2 * G2]; th = p[3 * G2]; tc = p[4 * G2];
        fx = (float)(s % 26); fy = (float)(s / 26); invG = 1.0f / 26.0f;
        aw = (a == 0) ? 1.875f  : ((a == 1) ? 3.875f  : 3.6875f);
        ah = (a == 0) ? 3.8125f : ((a == 1) ? 2.8125f : 7.4375f);
    } else {                            // g=52, anchors[0:3]/8
        constexpr int G2 = 2704;
        const int s = sg - 845;
        const float* __restrict__ p = f52 + (size_t)(b * 255 + a * 85) * G2 + s;
        tx = p[0]; ty = p[G2]; tw = p[2 * G2]; th = p[3 * G2]; tc = p[4 * G2];
        fx = (float)(s % 52); fy = (float)(s / 52); invG = 1.0f / 52.0f;
        aw = (a == 0) ? 1.25f  : ((a == 1) ? 2.0f  : 4.125f);
        ah = (a == 0) ? 1.625f : ((a == 1) ? 3.75f : 2.875f);
    }

    const float bx = (sigmoidf_(tx) + fx) * invG;
    const float by = (sigmoidf_(ty) + fy) * invG;
    const float bw = __expf(tw) * aw * invG;
    const float bh = __expf(th) * ah * invG;

    *(float4*)(out + (long long)tid * 4) = make_float4(bx, by, bw, bh);
    out[PRED_TOTAL + tid] = sigmoidf_(tc);
}

__global__ __launch_bounds__(256)
void yolo_fused_kernel(const float* __restrict__ f13,
                       const float* __restrict__ f26,
                       const float* __restrict__ f52,
                       float* __restrict__ out)
{
    // bijective XCD swizzle: NBLK % 8 == 0, each XCD gets a contiguous
    // chunk of the work so shared 128B lines stay in one L2.
    constexpr int CPX = NBLK / 8;
    const int bid = blockIdx.x;
    const int wid = (bid & 7) * CPX + (bid >> 3);

    int tid = wid * 256 + (int)threadIdx.x;

    if (tid < N52T) {                   // g=52, anchors[0:3]/8
        cls16x4<52, 845>(tid, f52, out);
        return;
    }
    tid -= N52T;
    if (tid < N26T) {                   // g=26, anchors[3:6]/16
        cls16x4<26, 169>(tid, f26, out);
        return;
    }
    tid -= N26T;
    if (tid < N13T) {                   // g=13, anchors[6:9]/32
        cls8x1<13, 0>(tid, f13, out);
        return;
    }
    tid -= N13T;
    if (tid < NPRD) {
        pred_conf(tid, f13, f26, f52, out);
    }
}

} // namespace

extern "C" void kernel_launch(void* const* d_in, const int* in_sizes, int n_in,
                              void* d_out, int out_size, void* d_ws, size_t ws_size,
                              hipStream_t stream)
{
    (void)in_sizes; (void)n_in; (void)out_size; (void)d_ws; (void)ws_size;
    yolo_fused_kernel<<<NBLK, 256, 0, stream>>>(
        (const float*)d_in[0], (const float*)d_in[1], (const float*)d_in[2],
        (float*)d_out);
}

// Round 8
// 95.507 us; speedup vs baseline: 1.2106x; 1.2106x over previous
//
#include <hip/hip_runtime.h>

// YOLOv3 decode, fused single kernel: 3 scales (g=13,26,52), B=64,
// 3 anchors x (80 classes + 5).
// Outputs (concatenated flat, f32):
//   box_pred [64][3549][3][4]
//   box_conf [64][3549][3][1]
//   box_prob [64][3549][3][80]  (softmax over classes, no-max variant)
//
// R7: wave-local LDS transpose. Input wants spatial dense across lanes,
// output wants classes dense across lanes — no direct mapping gives both.
// Lane layout h-high/sp-low: each load instr = 8 adjacent-lane runs of
// 64B contiguous (guaranteed coalescing). Softmax butterfly over
// xor 8,16,32. Results staged in a per-wave 16x84 LDS tile (no barrier,
// wave-private), re-read flat -> prob stores are dense 320B row runs.
// XCD swizzle removed (R6 lesson: null-to-negative for streaming).

namespace {

constexpr int BATCH   = 64;
constexpr int S_TOTAL = 3549;           // 169 + 676 + 2704
constexpr int NC      = 80;
constexpr long long PRED_TOTAL = (long long)BATCH * S_TOTAL * 3 * 4;  // 2,725,632
constexpr long long CONF_TOTAL = (long long)BATCH * S_TOTAL * 3;      //   681,408

constexpr int N52T = BATCH * 3 * (52 * 52 / 2) * 8;   // 2,076,672
constexpr int N26T = BATCH * 3 * (26 * 26 / 2) * 8;   //   519,168
constexpr int N13T = BATCH * 3 * (13 * 13) * 8;       //   259,584
constexpr int NPRD = BATCH * S_TOTAL * 3;             //   681,408
constexpr int NTOT = N52T + N26T + N13T + NPRD;       // 3,536,832
constexpr int NBLK = (NTOT + 255) / 256;              // 13,816

constexpr int LROW = 84;                // LDS row stride (floats), padded

__device__ __forceinline__ float sigmoidf_(float x) {
    return __builtin_amdgcn_rcpf(1.0f + __expf(-x));
}

// ---- classes, transposed-store path: lane = h*8 + sp (h-high, sp-low) ----
// Wave covers 8 position-pairs (16 positions); lane h owns classes
// [10h,10h+10) of pair sp. Loads: 8 adjacent lanes = 64B contiguous.
// Stores: via LDS tile, dense 320B row runs.
template <int G, int S_OFF>
__device__ __forceinline__ void clsT(int tid,
                                     const float* __restrict__ feat,
                                     float* __restrict__ out,
                                     float (*__restrict__ lds)[16][LROW])
{
    constexpr int G2  = G * G;
    constexpr int NPP = G2 / 2;

    const int lane  = tid & 63;
    const int sp    = lane & 7;          // position-pair within wave
    const int h     = (lane >> 3) & 7;   // class decade
    const int w     = (tid >> 6) & 3;    // wave within block
    const int wpair = (tid >> 6) * 8;    // wave's first global pair id

    const int pair = wpair + sp;
    const int ba   = pair / NPP;
    const int pp   = pair % NPP;
    const int a    = ba % 3;
    const int b    = ba / 3;
    const int s0   = pp * 2;

    const float* __restrict__ pc =
        feat + (size_t)(b * 255 + a * 85 + 5 + h * 10) * G2 + s0;

    float2 cls[10];
#pragma unroll
    for (int k = 0; k < 10; ++k)
        cls[k] = *(const float2*)(pc + (size_t)k * G2);

    // exp as loads land; pin results (20 live floats, no remat/spill)
    float sm0 = 0.f, sm1 = 0.f;
#pragma unroll
    for (int k = 0; k < 10; ++k) {
        cls[k].x = __expf(cls[k].x);
        cls[k].y = __expf(cls[k].y);
        asm volatile("" : "+v"(cls[k].x), "+v"(cls[k].y));
        sm0 += cls[k].x;
        sm1 += cls[k].y;
    }

    // butterfly across the h dimension (lanes sharing sp): xor 8,16,32
    sm0 += __shfl_xor(sm0, 8, 64);
    sm0 += __shfl_xor(sm0, 16, 64);
    sm0 += __shfl_xor(sm0, 32, 64);
    sm1 += __shfl_xor(sm1, 8, 64);
    sm1 += __shfl_xor(sm1, 16, 64);
    sm1 += __shfl_xor(sm1, 32, 64);
    const float r0 = __builtin_amdgcn_rcpf(sm0);
    const float r1 = __builtin_amdgcn_rcpf(sm1);

    // stash normalized probs into the wave-private LDS tile
    float* __restrict__ L0 = &lds[w][sp * 2 + 0][h * 10];
    float* __restrict__ L1 = &lds[w][sp * 2 + 1][h * 10];
#pragma unroll
    for (int k = 0; k < 10; ++k) {
        L0[k] = cls[k].x * r0;
        L1[k] = cls[k].y * r1;
    }

    // wave-local re-read, flat: 1280 floats = 640 float2; 10 per lane.
    // Consecutive lanes -> consecutive classes -> dense 320B row runs.
    float* __restrict__ probBase = out + PRED_TOTAL + CONF_TOTAL;
#pragma unroll
    for (int j = 0; j < 10; ++j) {
        const int qi  = j * 64 + lane;       // float2 index within wave tile
        const int row = qi / 40;             // 40 float2 per 80-float row
        const int col = (qi % 40) * 2;
        const float2 v = *(const float2*)&lds[w][row][col];

        const int pr  = wpair + (row >> 1);
        const int rba = pr / NPP;
        const int rpp = pr % NPP;
        const int rs  = rpp * 2 + (row & 1);
        const int rb  = rba / 3;
        const int ra  = rba % 3;
        const long long bsa = ((long long)rb * S_TOTAL + (S_OFF + rs)) * 3 + ra;
        *(float2*)(probBase + bsa * NC + col) = v;
    }
}

// ---- classes: 8-lane group x 1 position, scalar loads (g=13, odd G^2) ----
template <int G, int S_OFF>
__device__ __forceinline__ void cls8x1(int tid,
                                       const float* __restrict__ feat,
                                       float* __restrict__ out)
{
    constexpr int G2 = G * G;

    const int h   = tid & 7;            // classes [h*10, h*10+10)
    const int pos = tid >> 3;
    const int s   = pos % G2;
    const int ba  = pos / G2;
    const int a   = ba % 3;
    const int b   = ba / 3;

    const float* __restrict__ pc =
        feat + (size_t)(b * 255 + a * 85 + 5 + h * 10) * G2 + s;

    float cls[10];
#pragma unroll
    for (int k = 0; k < 10; ++k)
        cls[k] = pc[(size_t)k * G2];

    float sum = 0.0f;
#pragma unroll
    for (int k = 0; k < 10; ++k) {
        cls[k] = __expf(cls[k]);
        asm volatile("" : "+v"(cls[k]));
        sum += cls[k];
    }
    sum += __shfl_xor(sum, 1, 64);
    sum += __shfl_xor(sum, 2, 64);
    sum += __shfl_xor(sum, 4, 64);
    const float rs = __builtin_amdgcn_rcpf(sum);

    const long long bsa = ((long long)b * S_TOTAL + (S_OFF + s)) * 3 + a;
    float* __restrict__ pr = out + PRED_TOTAL + CONF_TOTAL + bsa * NC + h * 10;
#pragma unroll
    for (int k = 0; k < 10; k += 2)
        *(float2*)(pr + k) = make_float2(cls[k] * rs, cls[k + 1] * rs);
}

// ---- pred + conf: thread == bsa, fully coalesced float4/scalar writes ----
__device__ __forceinline__ void pred_conf(int tid,
                                          const float* __restrict__ f13,
                                          const float* __restrict__ f26,
                                          const float* __restrict__ f52,
                                          float* __restrict__ out)
{
    const int a  = tid % 3;
    const int r  = tid / 3;
    const int sg = r % S_TOTAL;
    const int b  = r / S_TOTAL;

    float tx, ty, tw, th, tc, fx, fy, invG, aw, ah;
    if (sg < 169) {                     // g=13, anchors[6:9]/32
        constexpr int G2 = 169;
        const int s = sg;
        const float* __restrict__ p = f13 + (size_t)(b * 255 + a * 85) * G2 + s;
        tx = p[0]; ty = p[G2]; tw = p[2 * G2]; th = p[3 * G2]; tc = p[4 * G2];
        fx = (float)(s % 13); fy = (float)(s / 13); invG = 1.0f / 13.0f;
        aw = (a == 0) ? 3.625f  : ((a == 1) ? 4.875f  : 11.65625f);
        ah = (a == 0) ? 2.8125f : ((a == 1) ? 6.1875f : 10.1875f);
    } else if (sg < 845) {              // g=26, anchors[3:6]/16
        constexpr int G2 = 676;
        const int s = sg - 169;
        const float* __restrict__ p = f26 + (size_t)(b * 255 + a * 85) * G2 + s;
        tx = p[0]; ty = p[G2]; tw = p[2 * G2]; th = p[3 * G2]; tc = p[4 * G2];
        fx = (float)(s % 26); fy = (float)(s / 26); invG = 1.0f / 26.0f;
        aw = (a == 0) ? 1.875f  : ((a == 1) ? 3.875f  : 3.6875f);
        ah = (a == 0) ? 3.8125f : ((a == 1) ? 2.8125f : 7.4375f);
    } else {                            // g=52, anchors[0:3]/8
        constexpr int G2 = 2704;
        const int s = sg - 845;
        const float* __restrict__ p = f52 + (size_t)(b * 255 + a * 85) * G2 + s;
        tx = p[0]; ty = p[G2]; tw = p[2 * G2]; th = p[3 * G2]; tc = p[4 * G2];
        fx = (float)(s % 52); fy = (float)(s / 52); invG = 1.0f / 52.0f;
        aw = (a == 0) ? 1.25f  : ((a == 1) ? 2.0f  : 4.125f);
        ah = (a == 0) ? 1.625f : ((a == 1) ? 3.75f : 2.875f);
    }

    const float bx = (sigmoidf_(tx) + fx) * invG;
    const float by = (sigmoidf_(ty) + fy) * invG;
    const float bw = __expf(tw) * aw * invG;
    const float bh = __expf(th) * ah * invG;

    *(float4*)(out + (long long)tid * 4) = make_float4(bx, by, bw, bh);
    out[PRED_TOTAL + tid] = sigmoidf_(tc);
}

__global__ __launch_bounds__(256)
void yolo_fused_kernel(const float* __restrict__ f13,
                       const float* __restrict__ f26,
                       const float* __restrict__ f52,
                       float* __restrict__ out)
{
    __shared__ float lds[4][16][LROW];   // per-wave 16x84 tile, 21504B

    int tid = blockIdx.x * 256 + (int)threadIdx.x;

    if (tid < N52T) {                   // g=52, anchors[0:3]/8
        clsT<52, 845>(tid, f52, out, lds);
        return;
    }
    tid -= N52T;
    if (tid < N26T) {                   // g=26, anchors[3:6]/16
        clsT<26, 169>(tid, f26, out, lds);
        return;
    }
    tid -= N26T;
    if (tid < N13T) {                   // g=13, anchors[6:9]/32
        cls8x1<13, 0>(tid, f13, out);
        return;
    }
    tid -= N13T;
    if (tid < NPRD) {
        pred_conf(tid, f13, f26, f52, out);
    }
}

} // namespace

extern "C" void kernel_launch(void* const* d_in, const int* in_sizes, int n_in,
                              void* d_out, int out_size, void* d_ws, size_t ws_size,
                              hipStream_t stream)
{
    (void)in_sizes; (void)n_in; (void)out_size; (void)d_ws; (void)ws_size;
    yolo_fused_kernel<<<NBLK, 256, 0, stream>>>(
        (const float*)d_in[0], (const float*)d_in[1], (const float*)d_in[2],
        (float*)d_out);
}

// Round 9
// 84.972 us; speedup vs baseline: 1.3607x; 1.1240x over previous
//
#include <hip/hip_runtime.h>

// YOLOv3 decode, fused single kernel: 3 scales (g=13,26,52), B=64,
// 3 anchors x (80 classes + 5).
// Outputs (concatenated flat, f32):
//   box_pred [64][3549][3][4]
//   box_conf [64][3549][3][1]
//   box_prob [64][3549][3][80]  (softmax over classes, no-max variant)
//
// R8 = R7 + NONTEMPORAL output stores (single change). Outputs are
// write-once (232MB/replay); default write-allocate evicts the input set
// from the 256MB L3 every replay (FETCH stuck at ~117-152MB). nt stores
// leave L3 to the read-mostly inputs. Loads keep default (cache) policy.

namespace {

constexpr int BATCH   = 64;
constexpr int S_TOTAL = 3549;           // 169 + 676 + 2704
constexpr int NC      = 80;
constexpr long long PRED_TOTAL = (long long)BATCH * S_TOTAL * 3 * 4;  // 2,725,632
constexpr long long CONF_TOTAL = (long long)BATCH * S_TOTAL * 3;      //   681,408

constexpr int N52T = BATCH * 3 * (52 * 52 / 2) * 8;   // 2,076,672
constexpr int N26T = BATCH * 3 * (26 * 26 / 2) * 8;   //   519,168
constexpr int N13T = BATCH * 3 * (13 * 13) * 8;       //   259,584
constexpr int NPRD = BATCH * S_TOTAL * 3;             //   681,408
constexpr int NTOT = N52T + N26T + N13T + NPRD;       // 3,536,832
constexpr int NBLK = (NTOT + 255) / 256;              // 13,816

constexpr int LROW = 84;                // LDS row stride (floats), padded

typedef float vf2 __attribute__((ext_vector_type(2)));
typedef float vf4 __attribute__((ext_vector_type(4)));

__device__ __forceinline__ void nt_store2(float* p, float a, float b) {
    vf2 v; v.x = a; v.y = b;
    __builtin_nontemporal_store(v, (vf2*)p);
}
__device__ __forceinline__ void nt_store4(float* p, float a, float b,
                                          float c, float d) {
    vf4 v; v.x = a; v.y = b; v.z = c; v.w = d;
    __builtin_nontemporal_store(v, (vf4*)p);
}

__device__ __forceinline__ float sigmoidf_(float x) {
    return __builtin_amdgcn_rcpf(1.0f + __expf(-x));
}

// ---- classes, transposed-store path: lane = h*8 + sp (h-high, sp-low) ----
template <int G, int S_OFF>
__device__ __forceinline__ void clsT(int tid,
                                     const float* __restrict__ feat,
                                     float* __restrict__ out,
                                     float (*__restrict__ lds)[16][LROW])
{
    constexpr int G2  = G * G;
    constexpr int NPP = G2 / 2;

    const int lane  = tid & 63;
    const int sp    = lane & 7;          // position-pair within wave
    const int h     = (lane >> 3) & 7;   // class decade
    const int w     = (tid >> 6) & 3;    // wave within block
    const int wpair = (tid >> 6) * 8;    // wave's first global pair id

    const int pair = wpair + sp;
    const int ba   = pair / NPP;
    const int pp   = pair % NPP;
    const int a    = ba % 3;
    const int b    = ba / 3;
    const int s0   = pp * 2;

    const float* __restrict__ pc =
        feat + (size_t)(b * 255 + a * 85 + 5 + h * 10) * G2 + s0;

    float2 cls[10];
#pragma unroll
    for (int k = 0; k < 10; ++k)
        cls[k] = *(const float2*)(pc + (size_t)k * G2);

    // exp as loads land; pin results (20 live floats, no remat/spill)
    float sm0 = 0.f, sm1 = 0.f;
#pragma unroll
    for (int k = 0; k < 10; ++k) {
        cls[k].x = __expf(cls[k].x);
        cls[k].y = __expf(cls[k].y);
        asm volatile("" : "+v"(cls[k].x), "+v"(cls[k].y));
        sm0 += cls[k].x;
        sm1 += cls[k].y;
    }

    // butterfly across the h dimension (lanes sharing sp): xor 8,16,32
    sm0 += __shfl_xor(sm0, 8, 64);
    sm0 += __shfl_xor(sm0, 16, 64);
    sm0 += __shfl_xor(sm0, 32, 64);
    sm1 += __shfl_xor(sm1, 8, 64);
    sm1 += __shfl_xor(sm1, 16, 64);
    sm1 += __shfl_xor(sm1, 32, 64);
    const float r0 = __builtin_amdgcn_rcpf(sm0);
    const float r1 = __builtin_amdgcn_rcpf(sm1);

    // stash normalized probs into the wave-private LDS tile
    float* __restrict__ L0 = &lds[w][sp * 2 + 0][h * 10];
    float* __restrict__ L1 = &lds[w][sp * 2 + 1][h * 10];
#pragma unroll
    for (int k = 0; k < 10; ++k) {
        L0[k] = cls[k].x * r0;
        L1[k] = cls[k].y * r1;
    }

    // wave-local re-read, flat: dense 320B row runs, nontemporal
    float* __restrict__ probBase = out + PRED_TOTAL + CONF_TOTAL;
#pragma unroll
    for (int j = 0; j < 10; ++j) {
        const int qi  = j * 64 + lane;       // float2 index within wave tile
        const int row = qi / 40;             // 40 float2 per 80-float row
        const int col = (qi % 40) * 2;
        const float2 v = *(const float2*)&lds[w][row][col];

        const int pr  = wpair + (row >> 1);
        const int rba = pr / NPP;
        const int rpp = pr % NPP;
        const int rs  = rpp * 2 + (row & 1);
        const int rb  = rba / 3;
        const int ra  = rba % 3;
        const long long bsa = ((long long)rb * S_TOTAL + (S_OFF + rs)) * 3 + ra;
        nt_store2(probBase + bsa * NC + col, v.x, v.y);
    }
}

// ---- classes: 8-lane group x 1 position, scalar loads (g=13, odd G^2) ----
template <int G, int S_OFF>
__device__ __forceinline__ void cls8x1(int tid,
                                       const float* __restrict__ feat,
                                       float* __restrict__ out)
{
    constexpr int G2 = G * G;

    const int h   = tid & 7;            // classes [h*10, h*10+10)
    const int pos = tid >> 3;
    const int s   = pos % G2;
    const int ba  = pos / G2;
    const int a   = ba % 3;
    const int b   = ba / 3;

    const float* __restrict__ pc =
        feat + (size_t)(b * 255 + a * 85 + 5 + h * 10) * G2 + s;

    float cls[10];
#pragma unroll
    for (int k = 0; k < 10; ++k)
        cls[k] = pc[(size_t)k * G2];

    float sum = 0.0f;
#pragma unroll
    for (int k = 0; k < 10; ++k) {
        cls[k] = __expf(cls[k]);
        asm volatile("" : "+v"(cls[k]));
        sum += cls[k];
    }
    sum += __shfl_xor(sum, 1, 64);
    sum += __shfl_xor(sum, 2, 64);
    sum += __shfl_xor(sum, 4, 64);
    const float rs = __builtin_amdgcn_rcpf(sum);

    const long long bsa = ((long long)b * S_TOTAL + (S_OFF + s)) * 3 + a;
    float* __restrict__ pr = out + PRED_TOTAL + CONF_TOTAL + bsa * NC + h * 10;
#pragma unroll
    for (int k = 0; k < 10; k += 2)
        nt_store2(pr + k, cls[k] * rs, cls[k + 1] * rs);
}

// ---- pred + conf: thread == bsa, fully coalesced float4/scalar writes ----
__device__ __forceinline__ void pred_conf(int tid,
                                          const float* __restrict__ f13,
                                          const float* __restrict__ f26,
                                          const float* __restrict__ f52,
                                          float* __restrict__ out)
{
    const int a  = tid % 3;
    const int r  = tid / 3;
    const int sg = r % S_TOTAL;
    const int b  = r / S_TOTAL;

    float tx, ty, tw, th, tc, fx, fy, invG, aw, ah;
    if (sg < 169) {                     // g=13, anchors[6:9]/32
        constexpr int G2 = 169;
        const int s = sg;
        const float* __restrict__ p = f13 + (size_t)(b * 255 + a * 85) * G2 + s;
        tx = p[0]; ty = p[G2]; tw = p[2 * G2]; th = p[3 * G2]; tc = p[4 * G2];
        fx = (float)(s % 13); fy = (float)(s / 13); invG = 1.0f / 13.0f;
        aw = (a == 0) ? 3.625f  : ((a == 1) ? 4.875f  : 11.65625f);
        ah = (a == 0) ? 2.8125f : ((a == 1) ? 6.1875f : 10.1875f);
    } else if (sg < 845) {              // g=26, anchors[3:6]/16
        constexpr int G2 = 676;
        const int s = sg - 169;
        const float* __restrict__ p = f26 + (size_t)(b * 255 + a * 85) * G2 + s;
        tx = p[0]; ty = p[G2]; tw = p[2 * G2]; th = p[3 * G2]; tc = p[4 * G2];
        fx = (float)(s % 26); fy = (float)(s / 26); invG = 1.0f / 26.0f;
        aw = (a == 0) ? 1.875f  : ((a == 1) ? 3.875f  : 3.6875f);
        ah = (a == 0) ? 3.8125f : ((a == 1) ? 2.8125f : 7.4375f);
    } else {                            // g=52, anchors[0:3]/8
        constexpr int G2 = 2704;
        const int s = sg - 845;
        const float* __restrict__ p = f52 + (size_t)(b * 255 + a * 85) * G2 + s;
        tx = p[0]; ty = p[G2]; tw = p[2 * G2]; th = p[3 * G2]; tc = p[4 * G2];
        fx = (float)(s % 52); fy = (float)(s / 52); invG = 1.0f / 52.0f;
        aw = (a == 0) ? 1.25f  : ((a == 1) ? 2.0f  : 4.125f);
        ah = (a == 0) ? 1.625f : ((a == 1) ? 3.75f : 2.875f);
    }

    const float bx = (sigmoidf_(tx) + fx) * invG;
    const float by = (sigmoidf_(ty) + fy) * invG;
    const float bw = __expf(tw) * aw * invG;
    const float bh = __expf(th) * ah * invG;

    nt_store4(out + (long long)tid * 4, bx, by, bw, bh);
    __builtin_nontemporal_store(sigmoidf_(tc), out + PRED_TOTAL + tid);
}

__global__ __launch_bounds__(256)
void yolo_fused_kernel(const float* __restrict__ f13,
                       const float* __restrict__ f26,
                       const float* __restrict__ f52,
                       float* __restrict__ out)
{
    __shared__ float lds[4][16][LROW];   // per-wave 16x84 tile, 21504B

    int tid = blockIdx.x * 256 + (int)threadIdx.x;

    if (tid < N52T) {                   // g=52, anchors[0:3]/8
        clsT<52, 845>(tid, f52, out, lds);
        return;
    }
    tid -= N52T;
    if (tid < N26T) {                   // g=26, anchors[3:6]/16
        clsT<26, 169>(tid, f26, out, lds);
        return;
    }
    tid -= N26T;
    if (tid < N13T) {                   // g=13, anchors[6:9]/32
        cls8x1<13, 0>(tid, f13, out);
        return;
    }
    tid -= N13T;
    if (tid < NPRD) {
        pred_conf(tid, f13, f26, f52, out);
    }
}

} // namespace

extern "C" void kernel_launch(void* const* d_in, const int* in_sizes, int n_in,
                              void* d_out, int out_size, void* d_ws, size_t ws_size,
                              hipStream_t stream)
{
    (void)in_sizes; (void)n_in; (void)out_size; (void)d_ws; (void)ws_size;
    yolo_fused_kernel<<<NBLK, 256, 0, stream>>>(
        (const float*)d_in[0], (const float*)d_in[1], (const float*)d_in[2],
        (float*)d_out);
}